// Round 1
// baseline (2416.990 us; speedup 1.0000x reference)
//
#include <hip/hip_runtime.h>
#include <cstddef>

#define N_NODES 50000
#define N_EDGES 800000
#define HDIM    128
#define TM      32   // edges (or nodes) per block

__device__ __forceinline__ float silu(float x) {
    return x / (1.0f + __expf(-x));
}

// One "layer" of the tile-matvec: 256 threads, TM=32 rows, 128 cols.
// Thread t computes col j = t&127 for rows (t>>7)*16 .. +15.
// X is an LDS tile [TM][XSTRIDE]; W is global [K][128] row-major.
template<int K, int XSTRIDE>
__device__ __forceinline__ void mlp_layer(const float* __restrict__ X,
                                          const float* __restrict__ W,
                                          float bias, int j, int half,
                                          float acc[16])
{
#pragma unroll
    for (int i = 0; i < 16; ++i) acc[i] = bias;
    int k = 0;
    for (; k + 4 <= K; k += 4) {
        float w0 = W[(size_t)(k + 0) * HDIM + j];
        float w1 = W[(size_t)(k + 1) * HDIM + j];
        float w2 = W[(size_t)(k + 2) * HDIM + j];
        float w3 = W[(size_t)(k + 3) * HDIM + j];
#pragma unroll
        for (int i = 0; i < 16; ++i) {
            const float4 xv = *(const float4*)(X + (half * 16 + i) * XSTRIDE + k);
            acc[i] = fmaf(xv.x, w0, acc[i]);
            acc[i] = fmaf(xv.y, w1, acc[i]);
            acc[i] = fmaf(xv.z, w2, acc[i]);
            acc[i] = fmaf(xv.w, w3, acc[i]);
        }
    }
    for (; k < K; ++k) {
        float w0 = W[(size_t)k * HDIM + j];
#pragma unroll
        for (int i = 0; i < 16; ++i)
            acc[i] = fmaf(X[(half * 16 + i) * XSTRIDE + k], w0, acc[i]);
    }
}

__global__ __launch_bounds__(256, 2)
void egnn_edge_kernel(const float* __restrict__ h,
                      const float* __restrict__ pos,
                      const int*   __restrict__ eidx,   // [2][E]
                      const float* __restrict__ eW0, const float* __restrict__ eb0,
                      const float* __restrict__ eW1, const float* __restrict__ eb1,
                      const float* __restrict__ cW0, const float* __restrict__ cb0,
                      const float* __restrict__ cW1,
                      float* __restrict__ m_i,          // [N][128] accum
                      float* __restrict__ pos_upd,      // [N][3]  accum
                      float* __restrict__ deg)          // [N]     accum
{
    __shared__ __align__(16) float xs[TM][260];      // h[row](128) | h[col](128) | radial(1)
    __shared__ __align__(16) float yb[2][TM][132];   // ping-pong activation tiles
    __shared__ float dif[TM][3];
    __shared__ int   rowb[TM];

    const int tid = threadIdx.x;
    const int e0  = blockIdx.x * TM;

    // ---- stage: gather h[row], h[col]; compute radial/diff ----
    {
        const int el  = tid >> 3;       // edge within tile (0..31)
        const int sub = tid & 7;        // 8 threads per edge
        const int e   = e0 + el;
        const int r   = eidx[e];
        const int c   = eidx[N_EDGES + e];
        const float4* hr = (const float4*)(h + (size_t)r * HDIM);
        const float4* hc = (const float4*)(h + (size_t)c * HDIM);
        float4* x0 = (float4*)&xs[el][0];
        float4* x1 = (float4*)&xs[el][128];
#pragma unroll
        for (int i = 0; i < 4; ++i) x0[i * 8 + sub] = hr[i * 8 + sub];
#pragma unroll
        for (int i = 0; i < 4; ++i) x1[i * 8 + sub] = hc[i * 8 + sub];
        if (sub == 0) {
            float dx = pos[(size_t)r * 3 + 0] - pos[(size_t)c * 3 + 0];
            float dy = pos[(size_t)r * 3 + 1] - pos[(size_t)c * 3 + 1];
            float dz = pos[(size_t)r * 3 + 2] - pos[(size_t)c * 3 + 2];
            dif[el][0] = dx; dif[el][1] = dy; dif[el][2] = dz;
            xs[el][256] = dx * dx + dy * dy + dz * dz;
            rowb[el] = r;
        }
    }
    __syncthreads();

    const int j    = tid & 127;
    const int half = tid >> 7;
    float acc[16];

    // ---- edge layer 1: silu(x @ eW0 + eb0) -> yb[0] ----
    mlp_layer<257, 260>(&xs[0][0], eW0, eb0[j], j, half, acc);
#pragma unroll
    for (int i = 0; i < 16; ++i) yb[0][half * 16 + i][j] = silu(acc[i]);
    __syncthreads();

    // ---- edge layer 2: m_ij = silu(y1 @ eW1 + eb1) -> yb[1] (+ keep in regs) ----
    mlp_layer<128, 132>(&yb[0][0][0], eW1, eb1[j], j, half, acc);
    float mval[16];
#pragma unroll
    for (int i = 0; i < 16; ++i) {
        float v = silu(acc[i]);
        mval[i] = v;
        yb[1][half * 16 + i][j] = v;
    }
    __syncthreads();

    // ---- coord layer 1: silu(m_ij @ cW0 + cb0) -> yb[0] ----
    mlp_layer<128, 132>(&yb[1][0][0], cW0, cb0[j], j, half, acc);
#pragma unroll
    for (int i = 0; i < 16; ++i) yb[0][half * 16 + i][j] = silu(acc[i]);

    // ---- scatter m_ij to m_i[row] (uses regs; independent of yb[0]) ----
#pragma unroll
    for (int i = 0; i < 16; ++i) {
        int e = half * 16 + i;
        atomicAdd(&m_i[(size_t)rowb[e] * HDIM + j], mval[i]);
    }
    __syncthreads();

    // ---- coord weight = (yb[0] . cW1) per edge; scatter pos_upd & deg ----
    {
        const int el  = tid >> 3;
        const int sub = tid & 7;
        float p = 0.f;
#pragma unroll
        for (int t = 0; t < 16; ++t) {
            int jj = sub * 16 + t;
            p += yb[0][el][jj] * cW1[jj];
        }
        p += __shfl_down(p, 4, 8);
        p += __shfl_down(p, 2, 8);
        p += __shfl_down(p, 1, 8);
        if (sub == 0) {
            float rad = xs[el][256];
            float inv = 1.0f / sqrtf(rad + 1e-8f);
            float cwv = p * inv;
            int   r   = rowb[el];
            atomicAdd(&pos_upd[(size_t)r * 3 + 0], dif[el][0] * cwv);
            atomicAdd(&pos_upd[(size_t)r * 3 + 1], dif[el][1] * cwv);
            atomicAdd(&pos_upd[(size_t)r * 3 + 2], dif[el][2] * cwv);
            atomicAdd(&deg[r], 1.0f);
        }
    }
}

__global__ __launch_bounds__(256)
void egnn_node_kernel(const float* __restrict__ h,
                      const float* __restrict__ pos,
                      const float* __restrict__ m_i,
                      const float* __restrict__ pos_upd,
                      const float* __restrict__ deg,
                      const float* __restrict__ nW0, const float* __restrict__ nb0,
                      const float* __restrict__ nW1, const float* __restrict__ nb1,
                      float* __restrict__ out_h,      // [N][128]
                      float* __restrict__ out_pos)    // [N][3]
{
    __shared__ __align__(16) float xs[TM][260];   // h(128) | m_i(128)
    __shared__ __align__(16) float yb[TM][132];

    const int tid = threadIdx.x;
    const int n0  = blockIdx.x * TM;

    // ---- stage ----
    {
        const int nl  = tid >> 3;
        const int sub = tid & 7;
        const int n   = n0 + nl;
        float4* x0 = (float4*)&xs[nl][0];
        float4* x1 = (float4*)&xs[nl][128];
        if (n < N_NODES) {
            const float4* hv = (const float4*)(h   + (size_t)n * HDIM);
            const float4* mv = (const float4*)(m_i + (size_t)n * HDIM);
#pragma unroll
            for (int i = 0; i < 4; ++i) x0[i * 8 + sub] = hv[i * 8 + sub];
#pragma unroll
            for (int i = 0; i < 4; ++i) x1[i * 8 + sub] = mv[i * 8 + sub];
        } else {
            float4 z = make_float4(0.f, 0.f, 0.f, 0.f);
#pragma unroll
            for (int i = 0; i < 4; ++i) { x0[i * 8 + sub] = z; x1[i * 8 + sub] = z; }
        }
    }
    __syncthreads();

    const int j    = tid & 127;
    const int half = tid >> 7;
    float acc[16];

    mlp_layer<256, 260>(&xs[0][0], nW0, nb0[j], j, half, acc);
#pragma unroll
    for (int i = 0; i < 16; ++i) yb[half * 16 + i][j] = silu(acc[i]);
    __syncthreads();

    mlp_layer<128, 132>(&yb[0][0], nW1, nb1[j], j, half, acc);
#pragma unroll
    for (int i = 0; i < 16; ++i) {
        int n = n0 + half * 16 + i;
        if (n < N_NODES)
            out_h[(size_t)n * HDIM + j] = h[(size_t)n * HDIM + j] + acc[i];
    }

    // ---- pos update ----
    if (tid < TM * 3) {
        int nl = tid / 3, d = tid % 3;
        int n  = n0 + nl;
        if (n < N_NODES) {
            float dv = deg[n];
            out_pos[(size_t)n * 3 + d] =
                pos[(size_t)n * 3 + d] + pos_upd[(size_t)n * 3 + d] / (dv + 1e-6f);
        }
    }
}

extern "C" void kernel_launch(void* const* d_in, const int* in_sizes, int n_in,
                              void* d_out, int out_size, void* d_ws, size_t ws_size,
                              hipStream_t stream) {
    const float* h    = (const float*)d_in[0];
    const float* pos  = (const float*)d_in[1];
    const int*   eidx = (const int*)  d_in[2];
    const float* eW0  = (const float*)d_in[3];
    const float* eb0  = (const float*)d_in[4];
    const float* eW1  = (const float*)d_in[5];
    const float* eb1  = (const float*)d_in[6];
    const float* nW0  = (const float*)d_in[7];
    const float* nb0  = (const float*)d_in[8];
    const float* nW1  = (const float*)d_in[9];
    const float* nb1  = (const float*)d_in[10];
    const float* cW0  = (const float*)d_in[11];
    const float* cb0  = (const float*)d_in[12];
    const float* cW1  = (const float*)d_in[13];

    float* out_h   = (float*)d_out;                       // [N][128]
    float* out_pos = out_h + (size_t)N_NODES * HDIM;      // [N][3]

    float* m_i     = (float*)d_ws;                        // [N][128]
    float* pos_upd = m_i + (size_t)N_NODES * HDIM;        // [N][3]
    float* deg     = pos_upd + (size_t)N_NODES * 3;       // [N]

    size_t zero_floats = (size_t)N_NODES * HDIM + (size_t)N_NODES * 3 + N_NODES;
    hipMemsetAsync(m_i, 0, zero_floats * sizeof(float), stream);

    egnn_edge_kernel<<<N_EDGES / TM, 256, 0, stream>>>(
        h, pos, eidx, eW0, eb0, eW1, eb1, cW0, cb0, cW1, m_i, pos_upd, deg);

    egnn_node_kernel<<<(N_NODES + TM - 1) / TM, 256, 0, stream>>>(
        h, pos, m_i, pos_upd, deg, nW0, nb0, nW1, nb1, out_h, out_pos);
}

// Round 2
// 540.571 us; speedup vs baseline: 4.4712x; 4.4712x over previous
//
#include <hip/hip_runtime.h>
#include <cstddef>

#define N_NODES 50000
#define N_EDGES 800000
#define HDIM    128
#define TME     64    // edges per block
#define TMN     64    // nodes per block

typedef __attribute__((ext_vector_type(4))) float f32x4;
typedef __attribute__((ext_vector_type(8))) short bf16x8;

__device__ __forceinline__ float silu(float x) {
    return x / (1.0f + __expf(-x));
}

__device__ __forceinline__ unsigned short f2bf(float f) {
    unsigned int u = __float_as_uint(f);
    u += 0x7fff + ((u >> 16) & 1);      // RNE
    return (unsigned short)(u >> 16);
}
__device__ __forceinline__ float bf2f(unsigned short u) {
    return __uint_as_float(((unsigned int)u) << 16);
}

// Packed-weight segment offsets (bf16 elements) inside the pack region:
//   eW0p [8cb][8ks][64lane][8]  = 32768
//   eW1p [8cb][4ks][64][8]      = 16384
//   cW0p                         = 16384
//   nW0p [8cb][8ks][64][8]      = 32768
//   nW1p                         = 16384
#define OFF_EW0 0
#define OFF_EW1 32768
#define OFF_CW0 49152
#define OFF_NW0 65536
#define OFF_NW1 98304
#define PACK_ELEMS 114688

// ---------------- weight pack kernel ----------------
// 224 fragment-groups (eW0:64, eW1:32, cW0:32, nW0:64, nW1:32) x 64 lanes.
__global__ void pack_weights(const float* __restrict__ eW0, const float* __restrict__ eW1,
                             const float* __restrict__ cW0, const float* __restrict__ nW0,
                             const float* __restrict__ nW1, unsigned short* __restrict__ pack)
{
    int g = blockIdx.x * blockDim.x + threadIdx.x;   // 0 .. 14335
    int f = g >> 6;
    int lane = g & 63;
    const float* W; int KS; int base;
    if (f < 64)       { W = eW0; KS = 8; base = OFF_EW0; }
    else if (f < 96)  { W = eW1; KS = 4; base = OFF_EW1; f -= 64; }
    else if (f < 128) { W = cW0; KS = 4; base = OFF_CW0; f -= 96; }
    else if (f < 192) { W = nW0; KS = 8; base = OFF_NW0; f -= 128; }
    else              { W = nW1; KS = 4; base = OFF_NW1; f -= 192; }
    int cb = f / KS, ks = f % KS;
    int col = cb * 16 + (lane & 15);
    int kbase = ks * 32 + ((lane >> 4) << 3);
#pragma unroll
    for (int j = 0; j < 8; ++j) {
        pack[(size_t)base + ((size_t)(f * KS + 0) * 0) +   // (kept simple below)
             ((size_t)((cb * KS + ks) * 64 + lane) * 8 + j)] = f2bf(W[(size_t)(kbase + j) * HDIM + col]);
    }
}

// ---------------- MFMA layer helper ----------------
// Wave `cb` (0..7) computes cols cb*16..+15 for 64 rows from LDS A-tile (XOR-swizzled).
// A-tile: row stride ROWB bytes, element (row,k) at row*ROWB + ((k*2) ^ ((row&7)<<4)).
template<int KS, int ROWB>
__device__ __forceinline__ void gemm_layer(const unsigned short* __restrict__ Bseg,
                                           const char* __restrict__ Xs,
                                           int lane, int cb, f32x4 acc[4])
{
    const bf16x8* bptr = (const bf16x8*)Bseg + (size_t)(cb * KS) * 64 + lane;
#pragma unroll
    for (int ks = 0; ks < KS; ++ks) {
        bf16x8 b = bptr[(size_t)ks * 64];
#pragma unroll
        for (int rb = 0; rb < 4; ++rb) {
            int row = rb * 16 + (lane & 15);
            int bir = ks * 64 + ((lane >> 4) << 4);
            bf16x8 a = *(const bf16x8*)(Xs + row * ROWB + (bir ^ ((row & 7) << 4)));
            acc[rb] = __builtin_amdgcn_mfma_f32_16x16x32_bf16(a, b, acc[rb], 0, 0, 0);
        }
    }
}

// ---------------- edge kernel ----------------
__global__ __launch_bounds__(512, 4)
void egnn_edge_kernel(const float* __restrict__ h,
                      const float* __restrict__ pos,
                      const int*   __restrict__ eidx,
                      const float* __restrict__ eW0,   // for row 256 (radial) fp32
                      const float* __restrict__ eb0, const float* __restrict__ eb1,
                      const float* __restrict__ cb0, const float* __restrict__ cW1,
                      const unsigned short* __restrict__ pack,
                      float* __restrict__ m_i,
                      float* __restrict__ pos_upd,
                      float* __restrict__ deg)
{
    __shared__ __align__(16) unsigned short Xs[TME * 256];  // 32KB  [64 rows][256 k] swizzled
    __shared__ __align__(16) unsigned short Ya[TME * 128];  // 16KB
    __shared__ __align__(16) unsigned short Yb[TME * 128];  // 16KB
    __shared__ float rad_s[TME];
    __shared__ float dif_s[TME][3];
    __shared__ int   rowb_s[TME];

    const int tid  = threadIdx.x;
    const int lane = tid & 63;
    const int cb   = tid >> 6;          // wave id = col block
    const int e0   = blockIdx.x * TME;

    // ---- stage: gather h[row] | h[col] as bf16 into swizzled Xs; radial/diff ----
    {
        const int el  = tid >> 3;       // 0..63
        const int sub = tid & 7;
        const int e   = e0 + el;
        const int r   = eidx[e];
        const int c   = eidx[N_EDGES + e];
        const float4* h4r = (const float4*)(h + (size_t)r * HDIM);
        const float4* h4c = (const float4*)(h + (size_t)c * HDIM);
#pragma unroll
        for (int q = 0; q < 4; ++q) {
            float4 fr = h4r[sub + q * 8];
            float4 fc = h4c[sub + q * 8];
            ushort4 ur = { f2bf(fr.x), f2bf(fr.y), f2bf(fr.z), f2bf(fr.w) };
            ushort4 uc = { f2bf(fc.x), f2bf(fc.y), f2bf(fc.z), f2bf(fc.w) };
            int er = (sub + q * 8) * 4 * 2;              // byte-in-row for row-part
            int ec = (128 + (sub + q * 8) * 4) * 2;      // byte-in-row for col-part
            *(ushort4*)((char*)Xs + el * 512 + (er ^ ((el & 7) << 4))) = ur;
            *(ushort4*)((char*)Xs + el * 512 + (ec ^ ((el & 7) << 4))) = uc;
        }
        if (sub == 0) {
            float dx = pos[(size_t)r * 3 + 0] - pos[(size_t)c * 3 + 0];
            float dy = pos[(size_t)r * 3 + 1] - pos[(size_t)c * 3 + 1];
            float dz = pos[(size_t)r * 3 + 2] - pos[(size_t)c * 3 + 2];
            dif_s[el][0] = dx; dif_s[el][1] = dy; dif_s[el][2] = dz;
            rad_s[el] = dx * dx + dy * dy + dz * dz;
            rowb_s[el] = r;
        }
    }
    __syncthreads();

    const int col = cb * 16 + (lane & 15);
    f32x4 acc[4];

    // ---- edge layer 1: K=256 + fp32 rank-1 radial term ----
    {
        float bias = eb0[col];
        float w256 = eW0[(size_t)256 * HDIM + col];
#pragma unroll
        for (int rb = 0; rb < 4; ++rb)
#pragma unroll
            for (int r = 0; r < 4; ++r) {
                int row = rb * 16 + ((lane >> 4) << 2) + r;
                acc[rb][r] = fmaf(rad_s[row], w256, bias);
            }
        gemm_layer<8, 512>(pack + OFF_EW0, (const char*)Xs, lane, cb, acc);
#pragma unroll
        for (int rb = 0; rb < 4; ++rb)
#pragma unroll
            for (int r = 0; r < 4; ++r) {
                int row = rb * 16 + ((lane >> 4) << 2) + r;
                float v = silu(acc[rb][r]);
                *(unsigned short*)((char*)Ya + row * 256 + ((col * 2) ^ ((row & 7) << 4))) = f2bf(v);
            }
    }
    __syncthreads();

    // ---- edge layer 2 (m_ij): K=128; scatter-add to m_i in fp32 ----
    {
        float bias = eb1[col];
#pragma unroll
        for (int rb = 0; rb < 4; ++rb) acc[rb] = f32x4{bias, bias, bias, bias};
        gemm_layer<4, 256>(pack + OFF_EW1, (const char*)Ya, lane, cb, acc);
#pragma unroll
        for (int rb = 0; rb < 4; ++rb)
#pragma unroll
            for (int r = 0; r < 4; ++r) {
                int row = rb * 16 + ((lane >> 4) << 2) + r;
                float v = silu(acc[rb][r]);
                *(unsigned short*)((char*)Yb + row * 256 + ((col * 2) ^ ((row & 7) << 4))) = f2bf(v);
                atomicAdd(&m_i[(size_t)rowb_s[row] * HDIM + col], v);
            }
    }
    __syncthreads();

    // ---- coord layer 1: K=128 ----
    {
        float bias = cb0[col];
#pragma unroll
        for (int rb = 0; rb < 4; ++rb) acc[rb] = f32x4{bias, bias, bias, bias};
        gemm_layer<4, 256>(pack + OFF_CW0, (const char*)Yb, lane, cb, acc);
#pragma unroll
        for (int rb = 0; rb < 4; ++rb)
#pragma unroll
            for (int r = 0; r < 4; ++r) {
                int row = rb * 16 + ((lane >> 4) << 2) + r;
                float v = silu(acc[rb][r]);
                *(unsigned short*)((char*)Ya + row * 256 + ((col * 2) ^ ((row & 7) << 4))) = f2bf(v);
            }
    }
    __syncthreads();

    // ---- coord weight dot + pos/deg scatter ----
    {
        const int el  = tid >> 3;
        const int sub = tid & 7;
        float p = 0.f;
#pragma unroll
        for (int i = 0; i < 16; ++i) {
            int jj = sub * 16 + i;
            unsigned short u = *(const unsigned short*)((char*)Ya + el * 256 + ((jj * 2) ^ ((el & 7) << 4)));
            p = fmaf(bf2f(u), cW1[jj], p);
        }
        p += __shfl_down(p, 4, 8);
        p += __shfl_down(p, 2, 8);
        p += __shfl_down(p, 1, 8);
        if (sub == 0) {
            float inv = 1.0f / sqrtf(rad_s[el] + 1e-8f);
            float cwv = p * inv;
            int   r   = rowb_s[el];
            atomicAdd(&pos_upd[(size_t)r * 3 + 0], dif_s[el][0] * cwv);
            atomicAdd(&pos_upd[(size_t)r * 3 + 1], dif_s[el][1] * cwv);
            atomicAdd(&pos_upd[(size_t)r * 3 + 2], dif_s[el][2] * cwv);
            atomicAdd(&deg[r], 1.0f);
        }
    }
}

// ---------------- node kernel ----------------
__global__ __launch_bounds__(512, 4)
void egnn_node_kernel(const float* __restrict__ h,
                      const float* __restrict__ pos,
                      const float* __restrict__ m_i,
                      const float* __restrict__ pos_upd,
                      const float* __restrict__ deg,
                      const float* __restrict__ nb0, const float* __restrict__ nb1,
                      const unsigned short* __restrict__ pack,
                      float* __restrict__ out_h,
                      float* __restrict__ out_pos)
{
    __shared__ __align__(16) unsigned short Xs[TMN * 256];  // [h | m_i] bf16 swizzled
    __shared__ __align__(16) unsigned short Ya[TMN * 128];

    const int tid  = threadIdx.x;
    const int lane = tid & 63;
    const int cb   = tid >> 6;
    const int n0   = blockIdx.x * TMN;

    // ---- pos finalize (independent) ----
    if (tid < TMN * 3) {
        int nl = tid / 3, d = tid % 3;
        int n  = n0 + nl;
        if (n < N_NODES) {
            out_pos[(size_t)n * 3 + d] =
                pos[(size_t)n * 3 + d] + pos_upd[(size_t)n * 3 + d] / (deg[n] + 1e-6f);
        }
    }

    // ---- stage ----
    {
        const int nl  = tid >> 3;
        const int sub = tid & 7;
        const int n   = n0 + nl;
        if (n < N_NODES) {
            const float4* h4 = (const float4*)(h   + (size_t)n * HDIM);
            const float4* m4 = (const float4*)(m_i + (size_t)n * HDIM);
#pragma unroll
            for (int q = 0; q < 4; ++q) {
                float4 fh = h4[sub + q * 8];
                float4 fm = m4[sub + q * 8];
                ushort4 uh = { f2bf(fh.x), f2bf(fh.y), f2bf(fh.z), f2bf(fh.w) };
                ushort4 um = { f2bf(fm.x), f2bf(fm.y), f2bf(fm.z), f2bf(fm.w) };
                int eh = (sub + q * 8) * 4 * 2;
                int em = (128 + (sub + q * 8) * 4) * 2;
                *(ushort4*)((char*)Xs + nl * 512 + (eh ^ ((nl & 7) << 4))) = uh;
                *(ushort4*)((char*)Xs + nl * 512 + (em ^ ((nl & 7) << 4))) = um;
            }
        } else {
            ushort4 z = {0, 0, 0, 0};
#pragma unroll
            for (int q = 0; q < 4; ++q) {
                int eh = (sub + q * 8) * 4 * 2;
                int em = (128 + (sub + q * 8) * 4) * 2;
                *(ushort4*)((char*)Xs + nl * 512 + (eh ^ ((nl & 7) << 4))) = z;
                *(ushort4*)((char*)Xs + nl * 512 + (em ^ ((nl & 7) << 4))) = z;
            }
        }
    }
    __syncthreads();

    const int col = cb * 16 + (lane & 15);
    f32x4 acc[4];

    // ---- node layer 1: K=256 ----
    {
        float bias = nb0[col];
#pragma unroll
        for (int rb = 0; rb < 4; ++rb) acc[rb] = f32x4{bias, bias, bias, bias};
        gemm_layer<8, 512>(pack + OFF_NW0, (const char*)Xs, lane, cb, acc);
#pragma unroll
        for (int rb = 0; rb < 4; ++rb)
#pragma unroll
            for (int r = 0; r < 4; ++r) {
                int row = rb * 16 + ((lane >> 4) << 2) + r;
                float v = silu(acc[rb][r]);
                *(unsigned short*)((char*)Ya + row * 256 + ((col * 2) ^ ((row & 7) << 4))) = f2bf(v);
            }
    }
    __syncthreads();

    // ---- node layer 2: K=128, no activation, + residual + nb1 ----
    {
        float bias = nb1[col];
#pragma unroll
        for (int rb = 0; rb < 4; ++rb) acc[rb] = f32x4{bias, bias, bias, bias};
        gemm_layer<4, 256>(pack + OFF_NW1, (const char*)Ya, lane, cb, acc);
#pragma unroll
        for (int rb = 0; rb < 4; ++rb)
#pragma unroll
            for (int r = 0; r < 4; ++r) {
                int row = rb * 16 + ((lane >> 4) << 2) + r;
                int n   = n0 + row;
                if (n < N_NODES)
                    out_h[(size_t)n * HDIM + col] = h[(size_t)n * HDIM + col] + acc[rb][r];
            }
    }
}

extern "C" void kernel_launch(void* const* d_in, const int* in_sizes, int n_in,
                              void* d_out, int out_size, void* d_ws, size_t ws_size,
                              hipStream_t stream) {
    const float* h    = (const float*)d_in[0];
    const float* pos  = (const float*)d_in[1];
    const int*   eidx = (const int*)  d_in[2];
    const float* eW0  = (const float*)d_in[3];
    const float* eb0  = (const float*)d_in[4];
    const float* eW1  = (const float*)d_in[5];
    const float* eb1  = (const float*)d_in[6];
    const float* nW0  = (const float*)d_in[7];
    const float* nb0  = (const float*)d_in[8];
    const float* nW1  = (const float*)d_in[9];
    const float* nb1  = (const float*)d_in[10];
    const float* cW0  = (const float*)d_in[11];
    const float* cb0  = (const float*)d_in[12];
    const float* cW1  = (const float*)d_in[13];

    float* out_h   = (float*)d_out;
    float* out_pos = out_h + (size_t)N_NODES * HDIM;

    float* m_i     = (float*)d_ws;                          // N*128 f32
    float* pos_upd = m_i + (size_t)N_NODES * HDIM;          // N*3
    float* deg     = pos_upd + (size_t)N_NODES * 3;         // N
    unsigned short* pack = (unsigned short*)(deg + N_NODES);

    size_t zero_floats = (size_t)N_NODES * HDIM + (size_t)N_NODES * 3 + N_NODES;
    hipMemsetAsync(m_i, 0, zero_floats * sizeof(float), stream);

    pack_weights<<<56, 256, 0, stream>>>(eW0, eW1, cW0, nW0, nW1, pack);

    egnn_edge_kernel<<<N_EDGES / TME, 512, 0, stream>>>(
        h, pos, eidx, eW0, eb0, eb1, cb0, cW1, pack, m_i, pos_upd, deg);

    egnn_node_kernel<<<(N_NODES + TMN - 1) / TMN, 512, 0, stream>>>(
        h, pos, m_i, pos_upd, deg, nb0, nb1, pack, out_h, out_pos);
}

// Round 3
// 540.326 us; speedup vs baseline: 4.4732x; 1.0005x over previous
//
#include <hip/hip_runtime.h>
#include <hip/hip_bf16.h>
#include <cstddef>

#define N_NODES 50000
#define N_EDGES 800000
#define HDIM    128
#define TME     64
#define TMN     64

typedef __attribute__((ext_vector_type(4))) float f32x4;
typedef __attribute__((ext_vector_type(8))) short bf16x8;

// pack offsets (bf16 elements)
#define OFF_EW0T 0
#define OFF_EW0B 16384
#define OFF_EW1  32768
#define OFF_CW0  49152
#define OFF_NW0  65536
#define OFF_NW1  98304
#define PACK_ELEMS 114688

__device__ __forceinline__ float silu(float x) {
    float e = __expf(-x);
    return __fdividef(x, 1.0f + e);
}
__device__ __forceinline__ unsigned short f2bf(float f) {
    union { __hip_bfloat16 h; unsigned short u; } cv;
    cv.h = __float2bfloat16(f);
    return cv.u;
}
__device__ __forceinline__ unsigned int f2bf2(float a, float b) {
    union { __hip_bfloat162 h; unsigned int u; } cv;
    cv.h = __float22bfloat162_rn(float2{a, b});
    return cv.u;
}
__device__ __forceinline__ float bf2f(unsigned short u) {
    return __uint_as_float(((unsigned int)u) << 16);
}

// ---------------- weight pack kernel ----------------
// 224 fragment-groups x 64 lanes; B-frag layout for mfma_f32_16x16x32_bf16:
// lane holds B[k = (lane>>4)*8 + j][col = cb*16 + (lane&15)].
__global__ void pack_weights(const float* __restrict__ eW0, const float* __restrict__ eW1,
                             const float* __restrict__ cW0, const float* __restrict__ nW0,
                             const float* __restrict__ nW1, unsigned short* __restrict__ pack)
{
    int g = blockIdx.x * blockDim.x + threadIdx.x;   // 0 .. 14335
    int f = g >> 6;
    int lane = g & 63;
    const float* W; int KS; int base; int rowoff = 0;
    if (f < 32)       { W = eW0; KS = 4; base = OFF_EW0T; }
    else if (f < 64)  { W = eW0; KS = 4; base = OFF_EW0B; f -= 32; rowoff = 128; }
    else if (f < 96)  { W = eW1; KS = 4; base = OFF_EW1;  f -= 64; }
    else if (f < 128) { W = cW0; KS = 4; base = OFF_CW0;  f -= 96; }
    else if (f < 192) { W = nW0; KS = 8; base = OFF_NW0;  f -= 128; }
    else              { W = nW1; KS = 4; base = OFF_NW1;  f -= 192; }
    int cb = f / KS, ks = f % KS;
    int col = cb * 16 + (lane & 15);
    int kbase = rowoff + ks * 32 + ((lane >> 4) << 3);
#pragma unroll
    for (int j = 0; j < 8; ++j)
        pack[(size_t)base + ((size_t)(f * 64 + lane) * 8 + j)] =
            f2bf(W[(size_t)(kbase + j) * HDIM + col]);
}

// ---------------- MFMA layer helper ----------------
// Wave cb computes cols cb*16..+15 for 64 rows from XOR-swizzled LDS A-tile.
// A element (row,k) at byte row*ROWB + ((k*2) ^ ((row&7)<<4)).
template<int KS, int ROWB>
__device__ __forceinline__ void gemm_layer(const unsigned short* __restrict__ Bseg,
                                           const char* __restrict__ Xs,
                                           int lane, int cb, f32x4 acc[4])
{
    const bf16x8* bptr = (const bf16x8*)Bseg + (size_t)(cb * KS) * 64 + lane;
#pragma unroll
    for (int ks = 0; ks < KS; ++ks) {
        bf16x8 b = bptr[(size_t)ks * 64];
#pragma unroll
        for (int rb = 0; rb < 4; ++rb) {
            int row = rb * 16 + (lane & 15);
            int bir = ks * 64 + ((lane >> 4) << 4);
            bf16x8 a = *(const bf16x8*)(Xs + row * ROWB + (bir ^ ((row & 7) << 4)));
            acc[rb] = __builtin_amdgcn_mfma_f32_16x16x32_bf16(a, b, acc[rb], 0, 0, 0);
        }
    }
}

// ---------------- dense precompute: H0r = h@eW0_top + eb0, H0c = h@eW0_bot ----------------
__global__ __launch_bounds__(512, 2)
void h0_kernel(const float* __restrict__ h, const float* __restrict__ eb0,
               const unsigned short* __restrict__ pack,
               unsigned short* __restrict__ H0r, unsigned short* __restrict__ H0c)
{
    __shared__ __align__(16) unsigned short Xs[TMN * 128];   // 16KB swizzled
    const int tid = threadIdx.x, lane = tid & 63, cb = tid >> 6;
    const int n0 = blockIdx.x * TMN;

    {
        const int nl = tid >> 3, sub = tid & 7, n = n0 + nl;
        if (n < N_NODES) {
            const float4* h4 = (const float4*)(h + (size_t)n * HDIM);
#pragma unroll
            for (int q = 0; q < 4; ++q) {
                float4 f = h4[sub + q * 8];
                uint2 u; u.x = f2bf2(f.x, f.y); u.y = f2bf2(f.z, f.w);
                *(uint2*)((char*)Xs + nl * 256 + (((sub + q * 8) * 8) ^ ((nl & 7) << 4))) = u;
            }
        } else {
            uint2 z{0, 0};
#pragma unroll
            for (int q = 0; q < 4; ++q)
                *(uint2*)((char*)Xs + nl * 256 + (((sub + q * 8) * 8) ^ ((nl & 7) << 4))) = z;
        }
    }
    __syncthreads();

    const int col = cb * 16 + (lane & 15);
    f32x4 acc[4];
    {
        float bias = eb0[col];
#pragma unroll
        for (int rb = 0; rb < 4; ++rb) acc[rb] = f32x4{bias, bias, bias, bias};
        gemm_layer<4, 256>(pack + OFF_EW0T, (const char*)Xs, lane, cb, acc);
#pragma unroll
        for (int rb = 0; rb < 4; ++rb)
#pragma unroll
            for (int r = 0; r < 4; ++r) {
                int row = rb * 16 + ((lane >> 4) << 2) + r, n = n0 + row;
                if (n < N_NODES) H0r[(size_t)n * HDIM + col] = f2bf(acc[rb][r]);
            }
    }
    {
#pragma unroll
        for (int rb = 0; rb < 4; ++rb) acc[rb] = f32x4{0.f, 0.f, 0.f, 0.f};
        gemm_layer<4, 256>(pack + OFF_EW0B, (const char*)Xs, lane, cb, acc);
#pragma unroll
        for (int rb = 0; rb < 4; ++rb)
#pragma unroll
            for (int r = 0; r < 4; ++r) {
                int row = rb * 16 + ((lane >> 4) << 2) + r, n = n0 + row;
                if (n < N_NODES) H0c[(size_t)n * HDIM + col] = f2bf(acc[rb][r]);
            }
    }
}

// ---------------- edge kernel ----------------
__global__ __launch_bounds__(512, 4)
void egnn_edge_kernel(const unsigned short* __restrict__ H0r,
                      const unsigned short* __restrict__ H0c,
                      const float* __restrict__ pos,
                      const int*   __restrict__ eidx,
                      const float* __restrict__ w256,      // eW0 row 256
                      const float* __restrict__ eb1, const float* __restrict__ cb0,
                      const float* __restrict__ cW1,
                      const unsigned short* __restrict__ pack,
                      float* __restrict__ m_i,
                      float* __restrict__ pos_upd,
                      float* __restrict__ deg)
{
    __shared__ __align__(16) unsigned short Ya[TME * 128];  // 16KB
    __shared__ __align__(16) unsigned short Yb[TME * 128];  // 16KB
    __shared__ float rad_s[TME];
    __shared__ float dif_s[TME][3];
    __shared__ int   rowb_s[TME];

    const int tid = threadIdx.x, lane = tid & 63, cb = tid >> 6;
    const int e0 = blockIdx.x * TME;

    // ---- phase 0: gather H0r[row]+H0c[col], add radial term, SiLU -> Ya ----
    {
        const int el = tid >> 3, sub = tid & 7, e = e0 + el;
        const int r = eidx[e];
        const int c = eidx[N_EDGES + e];
        float dx = pos[(size_t)r * 3 + 0] - pos[(size_t)c * 3 + 0];
        float dy = pos[(size_t)r * 3 + 1] - pos[(size_t)c * 3 + 1];
        float dz = pos[(size_t)r * 3 + 2] - pos[(size_t)c * 3 + 2];
        float rad = dx * dx + dy * dy + dz * dz;
        if (sub == 0) {
            rad_s[el] = rad;
            dif_s[el][0] = dx; dif_s[el][1] = dy; dif_s[el][2] = dz;
            rowb_s[el] = r;
        }
        const bf16x8* ar = (const bf16x8*)(H0r + (size_t)r * HDIM + sub * 16);
        const bf16x8* ac = (const bf16x8*)(H0c + (size_t)c * HDIM + sub * 16);
        bf16x8 a0 = ar[0], a1 = ar[1];
        bf16x8 c0 = ac[0], c1 = ac[1];
        const float4* wp = (const float4*)(w256 + sub * 16);
        float4 w4[4] = { wp[0], wp[1], wp[2], wp[3] };
        const float* wf = (const float*)w4;
        float v[16];
#pragma unroll
        for (int i = 0; i < 8; ++i) v[i]     = bf2f((unsigned short)a0[i]) + bf2f((unsigned short)c0[i]);
#pragma unroll
        for (int i = 0; i < 8; ++i) v[8 + i] = bf2f((unsigned short)a1[i]) + bf2f((unsigned short)c1[i]);
#pragma unroll
        for (int i = 0; i < 16; ++i) v[i] = silu(fmaf(rad, wf[i], v[i]));
#pragma unroll
        for (int c4 = 0; c4 < 4; ++c4) {
            uint2 u;
            u.x = f2bf2(v[c4 * 4 + 0], v[c4 * 4 + 1]);
            u.y = f2bf2(v[c4 * 4 + 2], v[c4 * 4 + 3]);
            *(uint2*)((char*)Ya + el * 256 + ((sub * 32 + c4 * 8) ^ ((el & 7) << 4))) = u;
        }
    }
    __syncthreads();

    const int col = cb * 16 + (lane & 15);
    f32x4 acc[4];

    // ---- phase 1: m_ij = silu(Ya @ eW1 + eb1); scatter to m_i; store Yb ----
    {
        float bias = eb1[col];
#pragma unroll
        for (int rb = 0; rb < 4; ++rb) acc[rb] = f32x4{bias, bias, bias, bias};
        gemm_layer<4, 256>(pack + OFF_EW1, (const char*)Ya, lane, cb, acc);
#pragma unroll
        for (int rb = 0; rb < 4; ++rb)
#pragma unroll
            for (int r = 0; r < 4; ++r) {
                int row = rb * 16 + ((lane >> 4) << 2) + r;
                float v = silu(acc[rb][r]);
                *(unsigned short*)((char*)Yb + row * 256 + ((col * 2) ^ ((row & 7) << 4))) = f2bf(v);
                atomicAdd(&m_i[(size_t)rowb_s[row] * HDIM + col], v);
            }
    }
    __syncthreads();

    // ---- phase 2: coord hidden = silu(Yb @ cW0 + cb0) -> Ya ----
    {
        float bias = cb0[col];
#pragma unroll
        for (int rb = 0; rb < 4; ++rb) acc[rb] = f32x4{bias, bias, bias, bias};
        gemm_layer<4, 256>(pack + OFF_CW0, (const char*)Yb, lane, cb, acc);
#pragma unroll
        for (int rb = 0; rb < 4; ++rb)
#pragma unroll
            for (int r = 0; r < 4; ++r) {
                int row = rb * 16 + ((lane >> 4) << 2) + r;
                *(unsigned short*)((char*)Ya + row * 256 + ((col * 2) ^ ((row & 7) << 4))) = f2bf(silu(acc[rb][r]));
            }
    }
    __syncthreads();

    // ---- phase 3: coord weight dot + pos/deg scatter ----
    {
        const int el = tid >> 3, sub = tid & 7;
        float p = 0.f;
#pragma unroll
        for (int i = 0; i < 16; ++i) {
            int jj = sub * 16 + i;
            unsigned short u = *(const unsigned short*)((char*)Ya + el * 256 + ((jj * 2) ^ ((el & 7) << 4)));
            p = fmaf(bf2f(u), cW1[jj], p);
        }
        p += __shfl_down(p, 4, 8);
        p += __shfl_down(p, 2, 8);
        p += __shfl_down(p, 1, 8);
        if (sub == 0) {
            float inv = 1.0f / sqrtf(rad_s[el] + 1e-8f);
            float cwv = p * inv;
            int   r   = rowb_s[el];
            atomicAdd(&pos_upd[(size_t)r * 3 + 0], dif_s[el][0] * cwv);
            atomicAdd(&pos_upd[(size_t)r * 3 + 1], dif_s[el][1] * cwv);
            atomicAdd(&pos_upd[(size_t)r * 3 + 2], dif_s[el][2] * cwv);
            atomicAdd(&deg[r], 1.0f);
        }
    }
}

// ---------------- node kernel ----------------
__global__ __launch_bounds__(512, 4)
void egnn_node_kernel(const float* __restrict__ h,
                      const float* __restrict__ pos,
                      const float* __restrict__ m_i,
                      const float* __restrict__ pos_upd,
                      const float* __restrict__ deg,
                      const float* __restrict__ nb0, const float* __restrict__ nb1,
                      const unsigned short* __restrict__ pack,
                      float* __restrict__ out_h,
                      float* __restrict__ out_pos)
{
    __shared__ __align__(16) unsigned short Xs[TMN * 256];
    __shared__ __align__(16) unsigned short Ya[TMN * 128];

    const int tid = threadIdx.x, lane = tid & 63, cb = tid >> 6;
    const int n0 = blockIdx.x * TMN;

    if (tid < TMN * 3) {
        int nl = tid / 3, d = tid % 3;
        int n = n0 + nl;
        if (n < N_NODES)
            out_pos[(size_t)n * 3 + d] =
                pos[(size_t)n * 3 + d] + pos_upd[(size_t)n * 3 + d] / (deg[n] + 1e-6f);
    }

    {
        const int nl = tid >> 3, sub = tid & 7, n = n0 + nl;
        if (n < N_NODES) {
            const float4* h4 = (const float4*)(h   + (size_t)n * HDIM);
            const float4* m4 = (const float4*)(m_i + (size_t)n * HDIM);
#pragma unroll
            for (int q = 0; q < 4; ++q) {
                float4 fh = h4[sub + q * 8];
                float4 fm = m4[sub + q * 8];
                uint2 uh; uh.x = f2bf2(fh.x, fh.y); uh.y = f2bf2(fh.z, fh.w);
                uint2 um; um.x = f2bf2(fm.x, fm.y); um.y = f2bf2(fm.z, fm.w);
                int eh = (sub + q * 8) * 8;
                int em = (128 + (sub + q * 8) * 4) * 2;
                *(uint2*)((char*)Xs + nl * 512 + (eh ^ ((nl & 7) << 4))) = uh;
                *(uint2*)((char*)Xs + nl * 512 + (em ^ ((nl & 7) << 4))) = um;
            }
        } else {
            uint2 z{0, 0};
#pragma unroll
            for (int q = 0; q < 4; ++q) {
                int eh = (sub + q * 8) * 8;
                int em = (128 + (sub + q * 8) * 4) * 2;
                *(uint2*)((char*)Xs + nl * 512 + (eh ^ ((nl & 7) << 4))) = z;
                *(uint2*)((char*)Xs + nl * 512 + (em ^ ((nl & 7) << 4))) = z;
            }
        }
    }
    __syncthreads();

    const int col = cb * 16 + (lane & 15);
    f32x4 acc[4];

    {
        float bias = nb0[col];
#pragma unroll
        for (int rb = 0; rb < 4; ++rb) acc[rb] = f32x4{bias, bias, bias, bias};
        gemm_layer<8, 512>(pack + OFF_NW0, (const char*)Xs, lane, cb, acc);
#pragma unroll
        for (int rb = 0; rb < 4; ++rb)
#pragma unroll
            for (int r = 0; r < 4; ++r) {
                int row = rb * 16 + ((lane >> 4) << 2) + r;
                *(unsigned short*)((char*)Ya + row * 256 + ((col * 2) ^ ((row & 7) << 4))) = f2bf(silu(acc[rb][r]));
            }
    }
    __syncthreads();

    {
        float bias = nb1[col];
#pragma unroll
        for (int rb = 0; rb < 4; ++rb) acc[rb] = f32x4{bias, bias, bias, bias};
        gemm_layer<4, 256>(pack + OFF_NW1, (const char*)Ya, lane, cb, acc);
#pragma unroll
        for (int rb = 0; rb < 4; ++rb)
#pragma unroll
            for (int r = 0; r < 4; ++r) {
                int row = rb * 16 + ((lane >> 4) << 2) + r, n = n0 + row;
                if (n < N_NODES)
                    out_h[(size_t)n * HDIM + col] = h[(size_t)n * HDIM + col] + acc[rb][r];
            }
    }
}

extern "C" void kernel_launch(void* const* d_in, const int* in_sizes, int n_in,
                              void* d_out, int out_size, void* d_ws, size_t ws_size,
                              hipStream_t stream) {
    const float* h    = (const float*)d_in[0];
    const float* pos  = (const float*)d_in[1];
    const int*   eidx = (const int*)  d_in[2];
    const float* eW0  = (const float*)d_in[3];
    const float* eb0  = (const float*)d_in[4];
    const float* eW1  = (const float*)d_in[5];
    const float* eb1  = (const float*)d_in[6];
    const float* nW0  = (const float*)d_in[7];
    const float* nb0  = (const float*)d_in[8];
    const float* nW1  = (const float*)d_in[9];
    const float* nb1  = (const float*)d_in[10];
    const float* cW0  = (const float*)d_in[11];
    const float* cb0  = (const float*)d_in[12];
    const float* cW1  = (const float*)d_in[13];

    float* out_h   = (float*)d_out;
    float* out_pos = out_h + (size_t)N_NODES * HDIM;

    float* m_i     = (float*)d_ws;                           // N*128 f32
    float* pos_upd = m_i + (size_t)N_NODES * HDIM;           // N*3
    float* deg     = pos_upd + (size_t)N_NODES * 3;          // N
    unsigned short* pack = (unsigned short*)(deg + N_NODES); // PACK_ELEMS bf16
    unsigned short* H0r  = pack + PACK_ELEMS;                // N*128 bf16
    unsigned short* H0c  = H0r + (size_t)N_NODES * HDIM;     // N*128 bf16

    size_t zero_floats = (size_t)N_NODES * HDIM + (size_t)N_NODES * 3 + N_NODES;
    hipMemsetAsync(m_i, 0, zero_floats * sizeof(float), stream);

    pack_weights<<<56, 256, 0, stream>>>(eW0, eW1, cW0, nW0, nW1, pack);

    h0_kernel<<<(N_NODES + TMN - 1) / TMN, 512, 0, stream>>>(h, eb0, pack, H0r, H0c);

    egnn_edge_kernel<<<N_EDGES / TME, 512, 0, stream>>>(
        H0r, H0c, pos, eidx, eW0 + (size_t)256 * HDIM, eb1, cb0, cW1,
        pack, m_i, pos_upd, deg);

    egnn_node_kernel<<<(N_NODES + TMN - 1) / TMN, 512, 0, stream>>>(
        h, pos, m_i, pos_upd, deg, nb0, nb1, pack, out_h, out_pos);
}